// Round 7
// baseline (578.953 us; speedup 1.0000x reference)
//
#include <hip/hip_runtime.h>

#define NN 100000
#define NE 1600000
#define DIM 64
#define NPB 128            // nodes per bin
#define NBIN 782           // ceil(NN / NPB)
#define NBINP 1024         // padded for scans
#define ECHUNK 2048        // edges per chunk
#define NCHUNKP 1024       // padded chunk count (real = 782)

// Per-chunk histogram over bins (LDS atomics only). gcounts layout: [bin][chunk].
__global__ __launch_bounds__(256) void k_hist(const int* __restrict__ dst,
                                              int* __restrict__ gcounts) {
    __shared__ int hist[NBINP];
    int tid = threadIdx.x, chunk = blockIdx.x;
    for (int j = tid; j < NBINP; j += 256) hist[j] = 0;
    __syncthreads();
    int base = chunk * ECHUNK;
    int lim = min(base + ECHUNK, NE);
    for (int i = base + tid; i < lim; i += 256)
        atomicAdd(&hist[dst[i] >> 7], 1);
    __syncthreads();
    for (int j = tid; j < NBINP; j += 256)
        gcounts[j * NCHUNKP + chunk] = hist[j];
}

// Per-bin exclusive scan over the chunk axis (row-contiguous, in place).
__global__ __launch_bounds__(256) void k_colscan(int* __restrict__ gcounts,
                                                 int* __restrict__ bintot) {
    __shared__ int sd[256];
    int t = threadIdx.x;
    int* p = gcounts + blockIdx.x * NCHUNKP;
    int v[4], s = 0;
    #pragma unroll
    for (int i = 0; i < 4; i++) { v[i] = p[t * 4 + i]; s += v[i]; }
    sd[t] = s;
    __syncthreads();
    for (int off = 1; off < 256; off <<= 1) {
        int x = (t >= off) ? sd[t - off] : 0;
        __syncthreads();
        sd[t] += x;
        __syncthreads();
    }
    int excl = sd[t] - s;
    #pragma unroll
    for (int i = 0; i < 4; i++) { p[t * 4 + i] = excl; excl += v[i]; }
    if (t == 255) bintot[blockIdx.x] = sd[255];
}

// Exclusive scan of 1024 bin totals -> binbase; also row_ptr[NN] = NE.
__global__ __launch_bounds__(256) void k_binscan(const int* __restrict__ bintot,
                                                 int* __restrict__ binbase,
                                                 int* __restrict__ row_ptr) {
    __shared__ int sd[256];
    int t = threadIdx.x;
    int v[4], s = 0;
    #pragma unroll
    for (int i = 0; i < 4; i++) { v[i] = bintot[t * 4 + i]; s += v[i]; }
    sd[t] = s;
    __syncthreads();
    for (int off = 1; off < 256; off <<= 1) {
        int x = (t >= off) ? sd[t - off] : 0;
        __syncthreads();
        sd[t] += x;
        __syncthreads();
    }
    int excl = sd[t] - s;
    #pragma unroll
    for (int i = 0; i < 4; i++) { binbase[t * 4 + i] = excl; excl += v[i]; }
    if (t == 255) { binbase[NBINP] = sd[255]; row_ptr[NN] = sd[255]; }
}

// Stable scatter of edges into their bin's contiguous range. No global atomics.
// meta = src (17b) | dst_local (7b) << 17
__global__ __launch_bounds__(256) void k_scatbin(const int* __restrict__ src,
                                                 const int* __restrict__ dst,
                                                 const float* __restrict__ w,
                                                 const int* __restrict__ gcounts,
                                                 const int* __restrict__ binbase,
                                                 int2* __restrict__ binned) {
    __shared__ int lcur[NBINP];
    int tid = threadIdx.x, chunk = blockIdx.x;
    for (int j = tid; j < NBINP; j += 256) lcur[j] = 0;
    __syncthreads();
    int base = chunk * ECHUNK;
    int lim = min(base + ECHUNK, NE);
    for (int i = base + tid; i < lim; i += 256) {
        int d = dst[i];
        int b = d >> 7;
        int r = atomicAdd(&lcur[b], 1);                       // LDS atomic
        int pos = binbase[b] + gcounts[b * NCHUNKP + chunk] + r;
        int meta = src[i] | ((d & 127) << 17);
        binned[pos] = make_int2(meta, __float_as_int(w[i]));
    }
}

// Per-bin: exact per-node grouping + row_ptr + dinv. All LDS-local, contiguous I/O.
__global__ __launch_bounds__(256) void k_group(const int2* __restrict__ binned,
                                               const int* __restrict__ binbase,
                                               int2* __restrict__ edata,
                                               int* __restrict__ row_ptr,
                                               float* __restrict__ dinv) {
    __shared__ int ndeg[NPB];
    __shared__ float nws[NPB];
    __shared__ int ncur[NPB];
    __shared__ int sd[NPB];
    int t = threadIdx.x, bin = blockIdx.x;
    int beg = binbase[bin], end = binbase[bin + 1];
    if (t < NPB) { ndeg[t] = 0; nws[t] = 0.f; }
    __syncthreads();
    for (int e = beg + t; e < end; e += 256) {
        int2 v = binned[e];
        int dl = ((unsigned)v.x) >> 17;
        atomicAdd(&ndeg[dl], 1);
        atomicAdd(&nws[dl], __int_as_float(v.y));
    }
    __syncthreads();
    int own = 0;
    if (t < NPB) { own = ndeg[t]; sd[t] = own; }
    __syncthreads();
    for (int off = 1; off < NPB; off <<= 1) {
        int x = (t >= off && t < NPB) ? sd[t - off] : 0;
        __syncthreads();
        if (t < NPB) sd[t] += x;
        __syncthreads();
    }
    if (t < NPB) {
        int excl = sd[t] - own;
        ncur[t] = excl;
        int node = bin * NPB + t;
        if (node < NN) {
            row_ptr[node] = beg + excl;
            dinv[node] = rsqrtf(1.0f + nws[t]);
        }
    }
    __syncthreads();
    for (int e = beg + t; e < end; e += 256) {
        int2 v = binned[e];
        int dl = ((unsigned)v.x) >> 17;
        int r = atomicAdd(&ncur[dl], 1);
        edata[beg + r] = make_int2(v.x & 0x1FFFF, v.y);
    }
}

// Bake dinv[src]*w into edata.y (edge-parallel, once). dst factor applied in layer.
__global__ __launch_bounds__(256) void k_norm(int2* __restrict__ edata,
                                              const float* __restrict__ dinv, int e) {
    int i = blockIdx.x * 256 + threadIdx.x;
    if (i < e) {
        int2 v = edata[i];
        edata[i].y = __float_as_int(__int_as_float(v.y) * dinv[v.x]);
    }
}

#define FMA4(acc, nm, h) \
    acc.x = fmaf(nm, h.x, acc.x); acc.y = fmaf(nm, h.y, acc.y); \
    acc.z = fmaf(nm, h.z, acc.z); acc.w = fmaf(nm, h.w, acc.w);

#define LOADROW(dstv, idx) \
    float4 dstv = *reinterpret_cast<const float4*>(Aprev + (size_t)(idx) * DIM + l * 4);

// Fused layer. One 16-lane group per node (4 consecutive nodes per wave).
// acc_inner = sum_e (dinv_s*w) * Aprev[s]; out_row = (acc_inner + dn*self)*dn; then @W+b.
template <int RELU>
__global__ __launch_bounds__(256) void k_layer(const int* __restrict__ row_ptr,
                                               const int2* __restrict__ edata,
                                               const float* __restrict__ Aprev,
                                               const float* __restrict__ W,
                                               const float* __restrict__ bias,
                                               const float* __restrict__ dinv,
                                               float* __restrict__ Anext, int n) {
    __shared__ float Wlds[64][64];       // 16 KB
    __shared__ float rowbuf[4][4][64];   // [wave][slot][ch] 4 KB
    int tid = threadIdx.x;
    #pragma unroll
    for (int t = tid; t < 4096; t += 256) Wlds[t >> 6][t & 63] = W[t];
    __syncthreads();

    int lane = tid & 63, wv = tid >> 6;
    int g = lane >> 4, l = lane & 15;
    float bl = bias[lane];

    int wave_id = blockIdx.x * 4 + wv;
    int stride = gridDim.x * 4 * 4;

    for (int base = wave_id * 4; base < n; base += stride) {
        int node = base + g;
        int beg = 0, end = 0;
        if (node < n) { beg = row_ptr[node]; end = row_ptr[node + 1]; }
        float4 acc = make_float4(0.f, 0.f, 0.f, 0.f);

        int e = beg;
        for (; e + 3 < end; e += 4) {     // stride-1, 4 loads in flight
            int2 e0 = edata[e], e1 = edata[e + 1], e2 = edata[e + 2], e3 = edata[e + 3];
            LOADROW(h0, e0.x); LOADROW(h1, e1.x); LOADROW(h2, e2.x); LOADROW(h3, e3.x);
            float n0 = __int_as_float(e0.y), n1 = __int_as_float(e1.y);
            float n2 = __int_as_float(e2.y), n3 = __int_as_float(e3.y);
            FMA4(acc, n0, h0); FMA4(acc, n1, h1);
            FMA4(acc, n2, h2); FMA4(acc, n3, h3);
        }
        if (e + 1 < end) {
            int2 e0 = edata[e], e1 = edata[e + 1];
            LOADROW(h0, e0.x); LOADROW(h1, e1.x);
            float n0 = __int_as_float(e0.y), n1 = __int_as_float(e1.y);
            FMA4(acc, n0, h0); FMA4(acc, n1, h1);
            e += 2;
        }
        if (e < end) {
            int2 e0 = edata[e];
            LOADROW(h0, e0.x);
            float n0 = __int_as_float(e0.y);
            FMA4(acc, n0, h0);
        }

        if (node < n) {   // self-loop + dst scale, stash row
            float dn = dinv[node];
            LOADROW(sv, node);
            acc.x = fmaf(dn, sv.x, acc.x) * dn;
            acc.y = fmaf(dn, sv.y, acc.y) * dn;
            acc.z = fmaf(dn, sv.z, acc.z) * dn;
            acc.w = fmaf(dn, sv.w, acc.w) * dn;
            *reinterpret_cast<float4*>(&rowbuf[wv][g][l * 4]) = acc;
        }
        __builtin_amdgcn_wave_barrier();

        // 4 rows @ W: k-outer, Wlds[k][lane] read once, rowbuf reads are broadcasts
        float o0 = 0.f, o1 = 0.f, o2 = 0.f, o3 = 0.f;
        #pragma unroll
        for (int k = 0; k < 64; k++) {
            float wk = Wlds[k][lane];
            o0 = fmaf(rowbuf[wv][0][k], wk, o0);
            o1 = fmaf(rowbuf[wv][1][k], wk, o1);
            o2 = fmaf(rowbuf[wv][2][k], wk, o2);
            o3 = fmaf(rowbuf[wv][3][k], wk, o3);
        }
        __builtin_amdgcn_wave_barrier();

        o0 += bl; o1 += bl; o2 += bl; o3 += bl;
        if (RELU) {
            o0 = fmaxf(o0, 0.f); o1 = fmaxf(o1, 0.f);
            o2 = fmaxf(o2, 0.f); o3 = fmaxf(o3, 0.f);
        }
        if (base + 0 < n) Anext[(size_t)(base + 0) * DIM + lane] = o0;
        if (base + 1 < n) Anext[(size_t)(base + 1) * DIM + lane] = o1;
        if (base + 2 < n) Anext[(size_t)(base + 2) * DIM + lane] = o2;
        if (base + 3 < n) Anext[(size_t)(base + 3) * DIM + lane] = o3;
    }
}

extern "C" void kernel_launch(void* const* d_in, const int* in_sizes, int n_in,
                              void* d_out, int out_size, void* d_ws, size_t ws_size,
                              hipStream_t stream) {
    const float* x  = (const float*)d_in[0];
    const int* ei   = (const int*)d_in[1];   // [2][NE] int32
    const float* ew = (const float*)d_in[2];
    const float* W1 = (const float*)d_in[3];
    const float* b1 = (const float*)d_in[4];
    const float* W2 = (const float*)d_in[5];
    const float* b2 = (const float*)d_in[6];
    const float* W3 = (const float*)d_in[7];
    const float* b3 = (const float*)d_in[8];
    float* out = (float*)d_out;

    const int* src = ei;
    const int* dst = ei + NE;

    auto align = [](size_t v) { return (v + 255) / 256 * 256; };
    char* ws = (char*)d_ws;
    int*   gcounts = (int*)ws;  ws += align((size_t)NBINP * NCHUNKP * 4);  // 4 MB
    int*   bintot  = (int*)ws;  ws += align((size_t)NBINP * 4);
    int*   binbase = (int*)ws;  ws += align(((size_t)NBINP + 1) * 4);
    int*   row_ptr = (int*)ws;  ws += align(((size_t)NN + 1) * 4);
    float* dinv    = (float*)ws; ws += align((size_t)NN * 4);
    int2*  binned  = (int2*)ws; ws += align((size_t)NE * 8);               // 12.8 MB
    int2*  edata   = (int2*)ws; ws += align((size_t)NE * 8);               // 12.8 MB
    float* A       = (float*)ws;                                           // 25.6 MB

    const int gE = (NE + 255) / 256;
    const int gL = 2048;

    // ---- deterministic CSR build: zero global atomics ----
    k_hist<<<NCHUNKP, 256, 0, stream>>>(dst, gcounts);
    k_colscan<<<NBINP, 256, 0, stream>>>(gcounts, bintot);
    k_binscan<<<1, 256, 0, stream>>>(bintot, binbase, row_ptr);
    k_scatbin<<<NCHUNKP, 256, 0, stream>>>(src, dst, ew, gcounts, binbase, binned);
    k_group<<<NBIN, 256, 0, stream>>>(binned, binbase, edata, row_ptr, dinv);
    k_norm<<<gE, 256, 0, stream>>>(edata, dinv, NE);

    // ---- fused layers (d_out doubles as layer-1 output) ----
    k_layer<1><<<gL, 256, 0, stream>>>(row_ptr, edata, x,   W1, b1, dinv, out, NN);
    k_layer<1><<<gL, 256, 0, stream>>>(row_ptr, edata, out, W2, b2, dinv, A,   NN);
    k_layer<0><<<gL, 256, 0, stream>>>(row_ptr, edata, A,   W3, b3, dinv, out, NN);
}

// Round 8
// 296.183 us; speedup vs baseline: 1.9547x; 1.9547x over previous
//
#include <hip/hip_runtime.h>

#define NN 100000
#define NE 1600000
#define DIM 64
#define NPB 128            // nodes per bin
#define NBIN 782           // ceil(NN / NPB)
#define NBINP 1024         // padded for scans
#define ECHUNK 2048        // edges per chunk
#define NCHUNKP 1024       // padded chunk count (real = 782)

// Per-chunk histogram over bins (LDS atomics only). gcounts layout: [bin][chunk].
__global__ __launch_bounds__(256) void k_hist(const int* __restrict__ dst,
                                              int* __restrict__ gcounts) {
    __shared__ int hist[NBINP];
    int tid = threadIdx.x, chunk = blockIdx.x;
    for (int j = tid; j < NBINP; j += 256) hist[j] = 0;
    __syncthreads();
    int base = chunk * ECHUNK;
    int lim = min(base + ECHUNK, NE);
    for (int i = base + tid; i < lim; i += 256)
        atomicAdd(&hist[dst[i] >> 7], 1);
    __syncthreads();
    for (int j = tid; j < NBINP; j += 256)
        gcounts[j * NCHUNKP + chunk] = hist[j];
}

// Per-bin exclusive scan over the chunk axis (row-contiguous, in place).
__global__ __launch_bounds__(256) void k_colscan(int* __restrict__ gcounts,
                                                 int* __restrict__ bintot) {
    __shared__ int sd[256];
    int t = threadIdx.x;
    int* p = gcounts + blockIdx.x * NCHUNKP;
    int v[4], s = 0;
    #pragma unroll
    for (int i = 0; i < 4; i++) { v[i] = p[t * 4 + i]; s += v[i]; }
    sd[t] = s;
    __syncthreads();
    for (int off = 1; off < 256; off <<= 1) {
        int x = (t >= off) ? sd[t - off] : 0;
        __syncthreads();
        sd[t] += x;
        __syncthreads();
    }
    int excl = sd[t] - s;
    #pragma unroll
    for (int i = 0; i < 4; i++) { p[t * 4 + i] = excl; excl += v[i]; }
    if (t == 255) bintot[blockIdx.x] = sd[255];
}

// Exclusive scan of 1024 bin totals -> binbase; also row_ptr[NN] = NE.
__global__ __launch_bounds__(256) void k_binscan(const int* __restrict__ bintot,
                                                 int* __restrict__ binbase,
                                                 int* __restrict__ row_ptr) {
    __shared__ int sd[256];
    int t = threadIdx.x;
    int v[4], s = 0;
    #pragma unroll
    for (int i = 0; i < 4; i++) { v[i] = bintot[t * 4 + i]; s += v[i]; }
    sd[t] = s;
    __syncthreads();
    for (int off = 1; off < 256; off <<= 1) {
        int x = (t >= off) ? sd[t - off] : 0;
        __syncthreads();
        sd[t] += x;
        __syncthreads();
    }
    int excl = sd[t] - s;
    #pragma unroll
    for (int i = 0; i < 4; i++) { binbase[t * 4 + i] = excl; excl += v[i]; }
    if (t == 255) { binbase[NBINP] = sd[255]; row_ptr[NN] = sd[255]; }
}

// Stable scatter of edges into their bin's contiguous range. No global atomics.
// meta = src (17b) | dst_local (7b) << 17
__global__ __launch_bounds__(256) void k_scatbin(const int* __restrict__ src,
                                                 const int* __restrict__ dst,
                                                 const float* __restrict__ w,
                                                 const int* __restrict__ gcounts,
                                                 const int* __restrict__ binbase,
                                                 int2* __restrict__ binned) {
    __shared__ int lcur[NBINP];
    int tid = threadIdx.x, chunk = blockIdx.x;
    for (int j = tid; j < NBINP; j += 256) lcur[j] = 0;
    __syncthreads();
    int base = chunk * ECHUNK;
    int lim = min(base + ECHUNK, NE);
    for (int i = base + tid; i < lim; i += 256) {
        int d = dst[i];
        int b = d >> 7;
        int r = atomicAdd(&lcur[b], 1);                       // LDS atomic
        int pos = binbase[b] + gcounts[b * NCHUNKP + chunk] + r;
        int meta = src[i] | ((d & 127) << 17);
        binned[pos] = make_int2(meta, __float_as_int(w[i]));
    }
}

// Per-bin: exact per-node grouping + row_ptr + dinv. All LDS-local, contiguous I/O.
__global__ __launch_bounds__(256) void k_group(const int2* __restrict__ binned,
                                               const int* __restrict__ binbase,
                                               int2* __restrict__ edata,
                                               int* __restrict__ row_ptr,
                                               float* __restrict__ dinv) {
    __shared__ int ndeg[NPB];
    __shared__ float nws[NPB];
    __shared__ int ncur[NPB];
    __shared__ int sd[NPB];
    int t = threadIdx.x, bin = blockIdx.x;
    int beg = binbase[bin], end = binbase[bin + 1];
    if (t < NPB) { ndeg[t] = 0; nws[t] = 0.f; }
    __syncthreads();
    for (int e = beg + t; e < end; e += 256) {
        int2 v = binned[e];
        int dl = ((unsigned)v.x) >> 17;
        atomicAdd(&ndeg[dl], 1);
        atomicAdd(&nws[dl], __int_as_float(v.y));
    }
    __syncthreads();
    int own = 0;
    if (t < NPB) { own = ndeg[t]; sd[t] = own; }
    __syncthreads();
    for (int off = 1; off < NPB; off <<= 1) {
        int x = (t >= off && t < NPB) ? sd[t - off] : 0;
        __syncthreads();
        if (t < NPB) sd[t] += x;
        __syncthreads();
    }
    if (t < NPB) {
        int excl = sd[t] - own;
        ncur[t] = excl;
        int node = bin * NPB + t;
        if (node < NN) {
            row_ptr[node] = beg + excl;
            dinv[node] = rsqrtf(1.0f + nws[t]);
        }
    }
    __syncthreads();
    for (int e = beg + t; e < end; e += 256) {
        int2 v = binned[e];
        int dl = ((unsigned)v.x) >> 17;
        int r = atomicAdd(&ncur[dl], 1);
        edata[beg + r] = make_int2(v.x & 0x1FFFF, v.y);
    }
}

// Bake dinv[src]*w into edata.y (edge-parallel, once). dst factor applied in layer.
__global__ __launch_bounds__(256) void k_norm(int2* __restrict__ edata,
                                              const float* __restrict__ dinv, int e) {
    int i = blockIdx.x * 256 + threadIdx.x;
    if (i < e) {
        int2 v = edata[i];
        edata[i].y = __float_as_int(__int_as_float(v.y) * dinv[v.x]);
    }
}

#define FMA4(acc, nm, h) \
    acc.x = fmaf(nm, h.x, acc.x); acc.y = fmaf(nm, h.y, acc.y); \
    acc.z = fmaf(nm, h.z, acc.z); acc.w = fmaf(nm, h.w, acc.w);

#define LOADROW(dstv, idx) \
    float4 dstv = *reinterpret_cast<const float4*>(Aprev + (size_t)(idx) * DIM + l * 4);

// Fused layer. One wave per node; each 16-lane group takes a CONTIGUOUS quarter
// of the node's edge list (4-deep unroll engages at deg>=16, the common case).
// acc = sum_e (dinv_s*w)*Aprev[s]; row = (acc + dn*self)*dn; out = row@W + b (+relu).
template <int RELU>
__global__ __launch_bounds__(256, 8) void k_layer(const int* __restrict__ row_ptr,
                                                  const int2* __restrict__ edata,
                                                  const float* __restrict__ Aprev,
                                                  const float* __restrict__ W,
                                                  const float* __restrict__ bias,
                                                  const float* __restrict__ dinv,
                                                  float* __restrict__ Anext, int n) {
    __shared__ float Wlds[64][64];     // 16 KB
    __shared__ float rowbuf[4][64];    // 1 KB
    int tid = threadIdx.x;
    #pragma unroll
    for (int t = tid; t < 4096; t += 256) Wlds[t >> 6][t & 63] = W[t];
    __syncthreads();

    int lane = tid & 63, wv = tid >> 6;
    int g = lane >> 4, l = lane & 15;
    float bl = bias[lane];

    int wave_id = blockIdx.x * 4 + wv;
    int nwaves = gridDim.x * 4;

    for (int node = wave_id; node < n; node += nwaves) {
        int beg = row_ptr[node], end = row_ptr[node + 1];
        int len = end - beg;
        int q = len >> 2, r = len & 3;
        int e = beg + g * q + min(g, r);       // contiguous quarter start
        int eend = e + q + (g < r ? 1 : 0);

        float4 acc = make_float4(0.f, 0.f, 0.f, 0.f);
        for (; e + 3 < eend; e += 4) {          // stride-1, 4 loads in flight
            int2 e0 = edata[e], e1 = edata[e + 1], e2 = edata[e + 2], e3 = edata[e + 3];
            LOADROW(h0, e0.x); LOADROW(h1, e1.x); LOADROW(h2, e2.x); LOADROW(h3, e3.x);
            float n0 = __int_as_float(e0.y), n1 = __int_as_float(e1.y);
            float n2 = __int_as_float(e2.y), n3 = __int_as_float(e3.y);
            FMA4(acc, n0, h0); FMA4(acc, n1, h1);
            FMA4(acc, n2, h2); FMA4(acc, n3, h3);
        }
        if (e + 1 < eend) {
            int2 e0 = edata[e], e1 = edata[e + 1];
            LOADROW(h0, e0.x); LOADROW(h1, e1.x);
            float n0 = __int_as_float(e0.y), n1 = __int_as_float(e1.y);
            FMA4(acc, n0, h0); FMA4(acc, n1, h1);
            e += 2;
        }
        if (e < eend) {
            int2 e0 = edata[e];
            LOADROW(h0, e0.x);
            float n0 = __int_as_float(e0.y);
            FMA4(acc, n0, h0);
        }

        // reduce the 4 quarters; every lane gets the full 4-ch sum
        acc.x += __shfl_xor(acc.x, 16); acc.y += __shfl_xor(acc.y, 16);
        acc.z += __shfl_xor(acc.z, 16); acc.w += __shfl_xor(acc.w, 16);
        acc.x += __shfl_xor(acc.x, 32); acc.y += __shfl_xor(acc.y, 32);
        acc.z += __shfl_xor(acc.z, 32); acc.w += __shfl_xor(acc.w, 32);

        if (g == 0) {  // self-loop + dst scale, stash row
            float dn = dinv[node];
            LOADROW(sv, node);
            acc.x = fmaf(dn, sv.x, acc.x) * dn;
            acc.y = fmaf(dn, sv.y, acc.y) * dn;
            acc.z = fmaf(dn, sv.z, acc.z) * dn;
            acc.w = fmaf(dn, sv.w, acc.w) * dn;
            *reinterpret_cast<float4*>(&rowbuf[wv][l * 4]) = acc;
        }
        __builtin_amdgcn_wave_barrier();

        // row @ W: rowbuf[wv][k] is an LDS broadcast, Wlds[k][lane] conflict-free
        float o = 0.f;
        #pragma unroll
        for (int k = 0; k < 64; k++)
            o = fmaf(rowbuf[wv][k], Wlds[k][lane], o);
        __builtin_amdgcn_wave_barrier();

        o += bl;
        if (RELU) o = fmaxf(o, 0.f);
        Anext[(size_t)node * DIM + lane] = o;
    }
}

extern "C" void kernel_launch(void* const* d_in, const int* in_sizes, int n_in,
                              void* d_out, int out_size, void* d_ws, size_t ws_size,
                              hipStream_t stream) {
    const float* x  = (const float*)d_in[0];
    const int* ei   = (const int*)d_in[1];   // [2][NE] int32
    const float* ew = (const float*)d_in[2];
    const float* W1 = (const float*)d_in[3];
    const float* b1 = (const float*)d_in[4];
    const float* W2 = (const float*)d_in[5];
    const float* b2 = (const float*)d_in[6];
    const float* W3 = (const float*)d_in[7];
    const float* b3 = (const float*)d_in[8];
    float* out = (float*)d_out;

    const int* src = ei;
    const int* dst = ei + NE;

    auto align = [](size_t v) { return (v + 255) / 256 * 256; };
    char* ws = (char*)d_ws;
    int*   gcounts = (int*)ws;  ws += align((size_t)NBINP * NCHUNKP * 4);  // 4 MB
    int*   bintot  = (int*)ws;  ws += align((size_t)NBINP * 4);
    int*   binbase = (int*)ws;  ws += align(((size_t)NBINP + 1) * 4);
    int*   row_ptr = (int*)ws;  ws += align(((size_t)NN + 1) * 4);
    float* dinv    = (float*)ws; ws += align((size_t)NN * 4);
    int2*  binned  = (int2*)ws; ws += align((size_t)NE * 8);               // 12.8 MB
    int2*  edata   = (int2*)ws; ws += align((size_t)NE * 8);               // 12.8 MB
    float* A       = (float*)ws;                                           // 25.6 MB

    const int gE = (NE + 255) / 256;
    const int gL = 2048;

    // ---- deterministic CSR build: zero global atomics ----
    k_hist<<<NCHUNKP, 256, 0, stream>>>(dst, gcounts);
    k_colscan<<<NBINP, 256, 0, stream>>>(gcounts, bintot);
    k_binscan<<<1, 256, 0, stream>>>(bintot, binbase, row_ptr);
    k_scatbin<<<NCHUNKP, 256, 0, stream>>>(src, dst, ew, gcounts, binbase, binned);
    k_group<<<NBIN, 256, 0, stream>>>(binned, binbase, edata, row_ptr, dinv);
    k_norm<<<gE, 256, 0, stream>>>(edata, dinv, NE);

    // ---- fused layers (d_out doubles as layer-1 output) ----
    k_layer<1><<<gL, 256, 0, stream>>>(row_ptr, edata, x,   W1, b1, dinv, out, NN);
    k_layer<1><<<gL, 256, 0, stream>>>(row_ptr, edata, out, W2, b2, dinv, A,   NN);
    k_layer<0><<<gL, 256, 0, stream>>>(row_ptr, edata, A,   W3, b3, dinv, out, NN);
}

// Round 9
// 272.930 us; speedup vs baseline: 2.1212x; 1.0852x over previous
//
#include <hip/hip_runtime.h>

#define NN 100000
#define NE 1600000
#define DIM 64
#define NPB 128            // nodes per bin
#define NBIN 782           // ceil(NN / NPB)
#define NBINP 1024         // padded for scans
#define ECHUNK 2048        // edges per chunk
#define NCHUNKP 1024       // padded chunk count (real = 782)

__device__ inline ushort f2bf(float f) {            // round-to-nearest-even
    unsigned u = __float_as_uint(f);
    unsigned r = u + 0x7FFFu + ((u >> 16) & 1u);
    return (ushort)(r >> 16);
}
__device__ inline float bf2f(ushort h) {
    return __uint_as_float(((unsigned)h) << 16);
}

// Per-chunk histogram over bins (LDS atomics only). gcounts layout: [bin][chunk].
__global__ __launch_bounds__(256) void k_hist(const int* __restrict__ dst,
                                              int* __restrict__ gcounts) {
    __shared__ int hist[NBINP];
    int tid = threadIdx.x, chunk = blockIdx.x;
    for (int j = tid; j < NBINP; j += 256) hist[j] = 0;
    __syncthreads();
    int base = chunk * ECHUNK;
    int lim = min(base + ECHUNK, NE);
    for (int i = base + tid; i < lim; i += 256)
        atomicAdd(&hist[dst[i] >> 7], 1);
    __syncthreads();
    for (int j = tid; j < NBINP; j += 256)
        gcounts[j * NCHUNKP + chunk] = hist[j];
}

// Per-bin exclusive scan over the chunk axis (row-contiguous, in place).
__global__ __launch_bounds__(256) void k_colscan(int* __restrict__ gcounts,
                                                 int* __restrict__ bintot) {
    __shared__ int sd[256];
    int t = threadIdx.x;
    int* p = gcounts + blockIdx.x * NCHUNKP;
    int v[4], s = 0;
    #pragma unroll
    for (int i = 0; i < 4; i++) { v[i] = p[t * 4 + i]; s += v[i]; }
    sd[t] = s;
    __syncthreads();
    for (int off = 1; off < 256; off <<= 1) {
        int x = (t >= off) ? sd[t - off] : 0;
        __syncthreads();
        sd[t] += x;
        __syncthreads();
    }
    int excl = sd[t] - s;
    #pragma unroll
    for (int i = 0; i < 4; i++) { p[t * 4 + i] = excl; excl += v[i]; }
    if (t == 255) bintot[blockIdx.x] = sd[255];
}

// Exclusive scan of 1024 bin totals -> binbase; also row_ptr[NN] = NE.
__global__ __launch_bounds__(256) void k_binscan(const int* __restrict__ bintot,
                                                 int* __restrict__ binbase,
                                                 int* __restrict__ row_ptr) {
    __shared__ int sd[256];
    int t = threadIdx.x;
    int v[4], s = 0;
    #pragma unroll
    for (int i = 0; i < 4; i++) { v[i] = bintot[t * 4 + i]; s += v[i]; }
    sd[t] = s;
    __syncthreads();
    for (int off = 1; off < 256; off <<= 1) {
        int x = (t >= off) ? sd[t - off] : 0;
        __syncthreads();
        sd[t] += x;
        __syncthreads();
    }
    int excl = sd[t] - s;
    #pragma unroll
    for (int i = 0; i < 4; i++) { binbase[t * 4 + i] = excl; excl += v[i]; }
    if (t == 255) { binbase[NBINP] = sd[255]; row_ptr[NN] = sd[255]; }
}

// Stable scatter of edges into their bin's contiguous range. No global atomics.
// meta = src (17b) | dst_local (7b) << 17
__global__ __launch_bounds__(256) void k_scatbin(const int* __restrict__ src,
                                                 const int* __restrict__ dst,
                                                 const float* __restrict__ w,
                                                 const int* __restrict__ gcounts,
                                                 const int* __restrict__ binbase,
                                                 int2* __restrict__ binned) {
    __shared__ int lcur[NBINP];
    int tid = threadIdx.x, chunk = blockIdx.x;
    for (int j = tid; j < NBINP; j += 256) lcur[j] = 0;
    __syncthreads();
    int base = chunk * ECHUNK;
    int lim = min(base + ECHUNK, NE);
    for (int i = base + tid; i < lim; i += 256) {
        int d = dst[i];
        int b = d >> 7;
        int r = atomicAdd(&lcur[b], 1);                       // LDS atomic
        int pos = binbase[b] + gcounts[b * NCHUNKP + chunk] + r;
        int meta = src[i] | ((d & 127) << 17);
        binned[pos] = make_int2(meta, __float_as_int(w[i]));
    }
}

// Per-bin: exact per-node grouping + row_ptr + dinv. All LDS-local, contiguous I/O.
__global__ __launch_bounds__(256) void k_group(const int2* __restrict__ binned,
                                               const int* __restrict__ binbase,
                                               int2* __restrict__ edata,
                                               int* __restrict__ row_ptr,
                                               float* __restrict__ dinv) {
    __shared__ int ndeg[NPB];
    __shared__ float nws[NPB];
    __shared__ int ncur[NPB];
    __shared__ int sd[NPB];
    int t = threadIdx.x, bin = blockIdx.x;
    int beg = binbase[bin], end = binbase[bin + 1];
    if (t < NPB) { ndeg[t] = 0; nws[t] = 0.f; }
    __syncthreads();
    for (int e = beg + t; e < end; e += 256) {
        int2 v = binned[e];
        int dl = ((unsigned)v.x) >> 17;
        atomicAdd(&ndeg[dl], 1);
        atomicAdd(&nws[dl], __int_as_float(v.y));
    }
    __syncthreads();
    int own = 0;
    if (t < NPB) { own = ndeg[t]; sd[t] = own; }
    __syncthreads();
    for (int off = 1; off < NPB; off <<= 1) {
        int x = (t >= off && t < NPB) ? sd[t - off] : 0;
        __syncthreads();
        if (t < NPB) sd[t] += x;
        __syncthreads();
    }
    if (t < NPB) {
        int excl = sd[t] - own;
        ncur[t] = excl;
        int node = bin * NPB + t;
        if (node < NN) {
            row_ptr[node] = beg + excl;
            dinv[node] = rsqrtf(1.0f + nws[t]);
        }
    }
    __syncthreads();
    for (int e = beg + t; e < end; e += 256) {
        int2 v = binned[e];
        int dl = ((unsigned)v.x) >> 17;
        int r = atomicAdd(&ncur[dl], 1);
        edata[beg + r] = make_int2(v.x & 0x1FFFF, v.y);
    }
}

// Bake dinv[src]*w into edata.y (edge-parallel, once). dst factor applied in layer.
__global__ __launch_bounds__(256) void k_norm(int2* __restrict__ edata,
                                              const float* __restrict__ dinv, int e) {
    int i = blockIdx.x * 256 + threadIdx.x;
    if (i < e) {
        int2 v = edata[i];
        edata[i].y = __float_as_int(__int_as_float(v.y) * dinv[v.x]);
    }
}

// Convert fp32 activations/input to bf16 gather table (vectorized x4).
__global__ __launch_bounds__(256) void k_cvt(const float* __restrict__ in,
                                             ushort* __restrict__ outb, int total4) {
    int i = blockIdx.x * 256 + threadIdx.x;
    if (i < total4) {
        float4 v = reinterpret_cast<const float4*>(in)[i];
        ushort4 o;
        o.x = f2bf(v.x); o.y = f2bf(v.y); o.z = f2bf(v.z); o.w = f2bf(v.w);
        reinterpret_cast<ushort4*>(outb)[i] = o;
    }
}

#define FMA4(acc, nm, h) \
    acc.x = fmaf(nm, h.x, acc.x); acc.y = fmaf(nm, h.y, acc.y); \
    acc.z = fmaf(nm, h.z, acc.z); acc.w = fmaf(nm, h.w, acc.w);

// bf16 row gather: 16 lanes x ushort4 (8B) = 128B row
#define LOADROWB(dstv, idx) \
    ushort4 dstv##q = *reinterpret_cast<const ushort4*>(Hb + (size_t)(idx) * DIM + l * 4); \
    float4 dstv = make_float4(bf2f(dstv##q.x), bf2f(dstv##q.y), bf2f(dstv##q.z), bf2f(dstv##q.w));

// Fused layer. One wave per node; each 16-lane group takes a CONTIGUOUS quarter
// of the node's edge list. Gather table is bf16; all math fp32.
// acc = sum_e (dinv_s*w)*Hb[s]; row = (acc + dn*self)*dn; out = row@W + b (+relu).
// RELU layers write bf16 to OutB; final layer writes fp32 to OutF.
template <int RELU>
__global__ __launch_bounds__(256, 8) void k_layer(const int* __restrict__ row_ptr,
                                                  const int2* __restrict__ edata,
                                                  const ushort* __restrict__ Hb,
                                                  const float* __restrict__ W,
                                                  const float* __restrict__ bias,
                                                  const float* __restrict__ dinv,
                                                  ushort* __restrict__ OutB,
                                                  float* __restrict__ OutF, int n) {
    __shared__ float Wlds[64][64];     // 16 KB
    __shared__ float rowbuf[4][64];    // 1 KB
    int tid = threadIdx.x;
    #pragma unroll
    for (int t = tid; t < 4096; t += 256) Wlds[t >> 6][t & 63] = W[t];
    __syncthreads();

    int lane = tid & 63, wv = tid >> 6;
    int g = lane >> 4, l = lane & 15;
    float bl = bias[lane];

    int wave_id = blockIdx.x * 4 + wv;
    int nwaves = gridDim.x * 4;

    for (int node = wave_id; node < n; node += nwaves) {
        int beg = row_ptr[node], end = row_ptr[node + 1];
        int len = end - beg;
        int q = len >> 2, r = len & 3;
        int e = beg + g * q + min(g, r);       // contiguous quarter start
        int eend = e + q + (g < r ? 1 : 0);

        float4 acc = make_float4(0.f, 0.f, 0.f, 0.f);
        for (; e + 3 < eend; e += 4) {          // stride-1, 4 gathers in flight
            int2 e0 = edata[e], e1 = edata[e + 1], e2 = edata[e + 2], e3 = edata[e + 3];
            LOADROWB(h0, e0.x); LOADROWB(h1, e1.x); LOADROWB(h2, e2.x); LOADROWB(h3, e3.x);
            float n0 = __int_as_float(e0.y), n1 = __int_as_float(e1.y);
            float n2 = __int_as_float(e2.y), n3 = __int_as_float(e3.y);
            FMA4(acc, n0, h0); FMA4(acc, n1, h1);
            FMA4(acc, n2, h2); FMA4(acc, n3, h3);
        }
        if (e + 1 < eend) {
            int2 e0 = edata[e], e1 = edata[e + 1];
            LOADROWB(h0, e0.x); LOADROWB(h1, e1.x);
            float n0 = __int_as_float(e0.y), n1 = __int_as_float(e1.y);
            FMA4(acc, n0, h0); FMA4(acc, n1, h1);
            e += 2;
        }
        if (e < eend) {
            int2 e0 = edata[e];
            LOADROWB(h0, e0.x);
            float n0 = __int_as_float(e0.y);
            FMA4(acc, n0, h0);
        }

        // reduce the 4 quarters; every lane gets the full 4-ch sum
        acc.x += __shfl_xor(acc.x, 16); acc.y += __shfl_xor(acc.y, 16);
        acc.z += __shfl_xor(acc.z, 16); acc.w += __shfl_xor(acc.w, 16);
        acc.x += __shfl_xor(acc.x, 32); acc.y += __shfl_xor(acc.y, 32);
        acc.z += __shfl_xor(acc.z, 32); acc.w += __shfl_xor(acc.w, 32);

        if (g == 0) {  // self-loop + dst scale, stash row
            float dn = dinv[node];
            LOADROWB(sv, node);
            acc.x = fmaf(dn, sv.x, acc.x) * dn;
            acc.y = fmaf(dn, sv.y, acc.y) * dn;
            acc.z = fmaf(dn, sv.z, acc.z) * dn;
            acc.w = fmaf(dn, sv.w, acc.w) * dn;
            *reinterpret_cast<float4*>(&rowbuf[wv][l * 4]) = acc;
        }
        __builtin_amdgcn_wave_barrier();

        // row @ W: rowbuf[wv][k] is an LDS broadcast, Wlds[k][lane] conflict-free
        float o = 0.f;
        #pragma unroll
        for (int k = 0; k < 64; k++)
            o = fmaf(rowbuf[wv][k], Wlds[k][lane], o);
        __builtin_amdgcn_wave_barrier();

        o += bl;
        if (RELU) {
            o = fmaxf(o, 0.f);
            OutB[(size_t)node * DIM + lane] = f2bf(o);
        } else {
            OutF[(size_t)node * DIM + lane] = o;
        }
    }
}

extern "C" void kernel_launch(void* const* d_in, const int* in_sizes, int n_in,
                              void* d_out, int out_size, void* d_ws, size_t ws_size,
                              hipStream_t stream) {
    const float* x  = (const float*)d_in[0];
    const int* ei   = (const int*)d_in[1];   // [2][NE] int32
    const float* ew = (const float*)d_in[2];
    const float* W1 = (const float*)d_in[3];
    const float* b1 = (const float*)d_in[4];
    const float* W2 = (const float*)d_in[5];
    const float* b2 = (const float*)d_in[6];
    const float* W3 = (const float*)d_in[7];
    const float* b3 = (const float*)d_in[8];
    float* out = (float*)d_out;

    const int* src = ei;
    const int* dst = ei + NE;

    auto align = [](size_t v) { return (v + 255) / 256 * 256; };
    char* ws = (char*)d_ws;
    // persistent through layers:
    int*   row_ptr = (int*)ws;   ws += align(((size_t)NN + 1) * 4);
    float* dinv    = (float*)ws; ws += align((size_t)NN * 4);
    int2*  edata   = (int2*)ws;  ws += align((size_t)NE * 8);              // 12.8 MB
    // build temporaries, later overlaid by Hb0 (all dead after k_group):
    char* temp = ws;
    int*  gcounts = (int*)temp;                 // 4 MB
    int*  bintot  = (int*)(temp + align((size_t)NBINP * NCHUNKP * 4));
    int*  binbase = (int*)((char*)bintot + align((size_t)NBINP * 4));
    int2* binned  = (int2*)((char*)binbase + align(((size_t)NBINP + 1) * 4)); // 12.8 MB
    ws += align((size_t)NBINP * NCHUNKP * 4) + align((size_t)NBINP * 4)
        + align(((size_t)NBINP + 1) * 4) + align((size_t)NE * 8);
    ushort* Hb0 = (ushort*)temp;                // 12.8 MB, overlays dead build temps
    // bf16 activations:
    ushort* A1b = (ushort*)ws; ws += align((size_t)NN * DIM * 2);          // 12.8 MB
    ushort* A2b = (ushort*)ws;                                             // 12.8 MB

    const int gE = (NE + 255) / 256;
    const int gC = (NN * DIM / 4 + 255) / 256;
    const int gL = 2048;

    // ---- deterministic CSR build: zero global atomics ----
    k_hist<<<NCHUNKP, 256, 0, stream>>>(dst, gcounts);
    k_colscan<<<NBINP, 256, 0, stream>>>(gcounts, bintot);
    k_binscan<<<1, 256, 0, stream>>>(bintot, binbase, row_ptr);
    k_scatbin<<<NCHUNKP, 256, 0, stream>>>(src, dst, ew, gcounts, binbase, binned);
    k_group<<<NBIN, 256, 0, stream>>>(binned, binbase, edata, row_ptr, dinv);
    k_norm<<<gE, 256, 0, stream>>>(edata, dinv, NE);
    k_cvt<<<gC, 256, 0, stream>>>(x, Hb0, NN * DIM / 4);   // after k_group (overlay)

    // ---- fused layers: bf16 gather tables, fp32 math ----
    k_layer<1><<<gL, 256, 0, stream>>>(row_ptr, edata, Hb0, W1, b1, dinv, A1b, nullptr, NN);
    k_layer<1><<<gL, 256, 0, stream>>>(row_ptr, edata, A1b, W2, b2, dinv, A2b, nullptr, NN);
    k_layer<0><<<gL, 256, 0, stream>>>(row_ptr, edata, A2b, W3, b3, dinv, nullptr, out, NN);
}

// Round 10
// 261.134 us; speedup vs baseline: 2.2171x; 1.0452x over previous
//
#include <hip/hip_runtime.h>

#define NN 100000
#define NE 1600000
#define DIM 64
#define NPB 128            // nodes per bin
#define NBIN 782           // ceil(NN / NPB)
#define NBINP 1024         // padded for scans
#define ECHUNK 2048        // edges per chunk
#define NCHUNKP 1024       // padded chunk count (real = 782)

__device__ inline ushort f2bf(float f) {            // round-to-nearest-even
    unsigned u = __float_as_uint(f);
    unsigned r = u + 0x7FFFu + ((u >> 16) & 1u);
    return (ushort)(r >> 16);
}
__device__ inline float bf2f(ushort h) {
    return __uint_as_float(((unsigned)h) << 16);
}

// Per-chunk histogram over bins (LDS atomics only). gcounts layout: [bin][chunk].
__global__ __launch_bounds__(256) void k_hist(const int* __restrict__ dst,
                                              int* __restrict__ gcounts) {
    __shared__ int hist[NBINP];
    int tid = threadIdx.x, chunk = blockIdx.x;
    for (int j = tid; j < NBINP; j += 256) hist[j] = 0;
    __syncthreads();
    int base = chunk * ECHUNK;
    int lim = min(base + ECHUNK, NE);
    for (int i = base + tid; i < lim; i += 256)
        atomicAdd(&hist[dst[i] >> 7], 1);
    __syncthreads();
    for (int j = tid; j < NBINP; j += 256)
        gcounts[j * NCHUNKP + chunk] = hist[j];
}

// Per-bin exclusive scan over the chunk axis (row-contiguous, in place).
__global__ __launch_bounds__(256) void k_colscan(int* __restrict__ gcounts,
                                                 int* __restrict__ bintot) {
    __shared__ int sd[256];
    int t = threadIdx.x;
    int* p = gcounts + blockIdx.x * NCHUNKP;
    int v[4], s = 0;
    #pragma unroll
    for (int i = 0; i < 4; i++) { v[i] = p[t * 4 + i]; s += v[i]; }
    sd[t] = s;
    __syncthreads();
    for (int off = 1; off < 256; off <<= 1) {
        int x = (t >= off) ? sd[t - off] : 0;
        __syncthreads();
        sd[t] += x;
        __syncthreads();
    }
    int excl = sd[t] - s;
    #pragma unroll
    for (int i = 0; i < 4; i++) { p[t * 4 + i] = excl; excl += v[i]; }
    if (t == 255) bintot[blockIdx.x] = sd[255];
}

// Exclusive scan of 1024 bin totals -> binbase; also row_ptr[NN] = NE.
__global__ __launch_bounds__(256) void k_binscan(const int* __restrict__ bintot,
                                                 int* __restrict__ binbase,
                                                 int* __restrict__ row_ptr) {
    __shared__ int sd[256];
    int t = threadIdx.x;
    int v[4], s = 0;
    #pragma unroll
    for (int i = 0; i < 4; i++) { v[i] = bintot[t * 4 + i]; s += v[i]; }
    sd[t] = s;
    __syncthreads();
    for (int off = 1; off < 256; off <<= 1) {
        int x = (t >= off) ? sd[t - off] : 0;
        __syncthreads();
        sd[t] += x;
        __syncthreads();
    }
    int excl = sd[t] - s;
    #pragma unroll
    for (int i = 0; i < 4; i++) { binbase[t * 4 + i] = excl; excl += v[i]; }
    if (t == 255) { binbase[NBINP] = sd[255]; row_ptr[NN] = sd[255]; }
}

// Stable scatter of edges into their bin's contiguous range. No global atomics.
// meta = src (17b) | dst_local (7b) << 17
__global__ __launch_bounds__(256) void k_scatbin(const int* __restrict__ src,
                                                 const int* __restrict__ dst,
                                                 const float* __restrict__ w,
                                                 const int* __restrict__ gcounts,
                                                 const int* __restrict__ binbase,
                                                 int2* __restrict__ binned) {
    __shared__ int lcur[NBINP];
    int tid = threadIdx.x, chunk = blockIdx.x;
    for (int j = tid; j < NBINP; j += 256) lcur[j] = 0;
    __syncthreads();
    int base = chunk * ECHUNK;
    int lim = min(base + ECHUNK, NE);
    for (int i = base + tid; i < lim; i += 256) {
        int d = dst[i];
        int b = d >> 7;
        int r = atomicAdd(&lcur[b], 1);                       // LDS atomic
        int pos = binbase[b] + gcounts[b * NCHUNKP + chunk] + r;
        int meta = src[i] | ((d & 127) << 17);
        binned[pos] = make_int2(meta, __float_as_int(w[i]));
    }
}

// Per-bin: exact per-node grouping + row_ptr + dinv. All LDS-local, contiguous I/O.
__global__ __launch_bounds__(256) void k_group(const int2* __restrict__ binned,
                                               const int* __restrict__ binbase,
                                               int2* __restrict__ edata,
                                               int* __restrict__ row_ptr,
                                               float* __restrict__ dinv) {
    __shared__ int ndeg[NPB];
    __shared__ float nws[NPB];
    __shared__ int ncur[NPB];
    __shared__ int sd[NPB];
    int t = threadIdx.x, bin = blockIdx.x;
    int beg = binbase[bin], end = binbase[bin + 1];
    if (t < NPB) { ndeg[t] = 0; nws[t] = 0.f; }
    __syncthreads();
    for (int e = beg + t; e < end; e += 256) {
        int2 v = binned[e];
        int dl = ((unsigned)v.x) >> 17;
        atomicAdd(&ndeg[dl], 1);
        atomicAdd(&nws[dl], __int_as_float(v.y));
    }
    __syncthreads();
    int own = 0;
    if (t < NPB) { own = ndeg[t]; sd[t] = own; }
    __syncthreads();
    for (int off = 1; off < NPB; off <<= 1) {
        int x = (t >= off && t < NPB) ? sd[t - off] : 0;
        __syncthreads();
        if (t < NPB) sd[t] += x;
        __syncthreads();
    }
    if (t < NPB) {
        int excl = sd[t] - own;
        ncur[t] = excl;
        int node = bin * NPB + t;
        if (node < NN) {
            row_ptr[node] = beg + excl;
            dinv[node] = rsqrtf(1.0f + nws[t]);
        }
    }
    __syncthreads();
    for (int e = beg + t; e < end; e += 256) {
        int2 v = binned[e];
        int dl = ((unsigned)v.x) >> 17;
        int r = atomicAdd(&ncur[dl], 1);
        edata[beg + r] = make_int2(v.x & 0x1FFFF, v.y);
    }
}

// Bake dinv[src]*w into edata.y (edge-parallel, once). dst factor applied in layer.
__global__ __launch_bounds__(256) void k_norm(int2* __restrict__ edata,
                                              const float* __restrict__ dinv, int e) {
    int i = blockIdx.x * 256 + threadIdx.x;
    if (i < e) {
        int2 v = edata[i];
        edata[i].y = __float_as_int(__int_as_float(v.y) * dinv[v.x]);
    }
}

// Convert fp32 activations/input to bf16 gather table (vectorized x4).
__global__ __launch_bounds__(256) void k_cvt(const float* __restrict__ in,
                                             ushort* __restrict__ outb, int total4) {
    int i = blockIdx.x * 256 + threadIdx.x;
    if (i < total4) {
        float4 v = reinterpret_cast<const float4*>(in)[i];
        ushort4 o;
        o.x = f2bf(v.x); o.y = f2bf(v.y); o.z = f2bf(v.z); o.w = f2bf(v.w);
        reinterpret_cast<ushort4*>(outb)[i] = o;
    }
}

#define FMA4(acc, nm, h) \
    acc.x = fmaf(nm, h.x, acc.x); acc.y = fmaf(nm, h.y, acc.y); \
    acc.z = fmaf(nm, h.z, acc.z); acc.w = fmaf(nm, h.w, acc.w);

// bf16 row gather: 16 lanes x ushort4 (8B) = 128B row
#define LOADROWB(dstv, idx) \
    ushort4 dstv##q = *reinterpret_cast<const ushort4*>(Hb + (size_t)(idx) * DIM + l * 4); \
    float4 dstv = make_float4(bf2f(dstv##q.x), bf2f(dstv##q.y), bf2f(dstv##q.z), bf2f(dstv##q.w));

// Fused layer. ONE NODE PER 16-LANE GROUP (4 consecutive nodes per wave).
// Each group owns its node's full contiguous edge list -> all 4 groups' loads
// (16 rows + 4 edata) are independent and in flight together; no cross-group
// reduce needed (a group's 16 lanes hold all 64 channels of its node).
template <int RELU>
__global__ __launch_bounds__(256, 8) void k_layer(const int* __restrict__ row_ptr,
                                                  const int2* __restrict__ edata,
                                                  const ushort* __restrict__ Hb,
                                                  const float* __restrict__ W,
                                                  const float* __restrict__ bias,
                                                  const float* __restrict__ dinv,
                                                  ushort* __restrict__ OutB,
                                                  float* __restrict__ OutF, int n) {
    __shared__ float Wlds[64][64];       // 16 KB
    __shared__ float rowbuf[4][4][64];   // [wave][group/node][ch] 4 KB
    int tid = threadIdx.x;
    #pragma unroll
    for (int t = tid; t < 4096; t += 256) Wlds[t >> 6][t & 63] = W[t];
    __syncthreads();

    int lane = tid & 63, wv = tid >> 6;
    int g = lane >> 4, l = lane & 15;
    float bl = bias[lane];

    int wave_id = blockIdx.x * 4 + wv;
    int nwaves = gridDim.x * 4;

    for (int base = wave_id * 4; base < n; base += nwaves * 4) {
        int node = base + g;
        bool valid = node < n;
        int beg = 0, end = 0;
        float dn = 0.f;
        if (valid) { beg = row_ptr[node]; end = row_ptr[node + 1]; dn = dinv[node]; }
        // self-row load issued early (independent of edge loop)
        int snode = valid ? node : 0;
        ushort4 svq = *reinterpret_cast<const ushort4*>(Hb + (size_t)snode * DIM + l * 4);

        float4 acc = make_float4(0.f, 0.f, 0.f, 0.f);
        int e = beg;
        for (; e + 3 < end; e += 4) {          // stride-1, 4 gathers in flight/group
            int2 e0 = edata[e], e1 = edata[e + 1], e2 = edata[e + 2], e3 = edata[e + 3];
            LOADROWB(h0, e0.x); LOADROWB(h1, e1.x); LOADROWB(h2, e2.x); LOADROWB(h3, e3.x);
            float n0 = __int_as_float(e0.y), n1 = __int_as_float(e1.y);
            float n2 = __int_as_float(e2.y), n3 = __int_as_float(e3.y);
            FMA4(acc, n0, h0); FMA4(acc, n1, h1);
            FMA4(acc, n2, h2); FMA4(acc, n3, h3);
        }
        if (e + 1 < end) {
            int2 e0 = edata[e], e1 = edata[e + 1];
            LOADROWB(h0, e0.x); LOADROWB(h1, e1.x);
            float n0 = __int_as_float(e0.y), n1 = __int_as_float(e1.y);
            FMA4(acc, n0, h0); FMA4(acc, n1, h1);
            e += 2;
        }
        if (e < end) {
            int2 e0 = edata[e];
            LOADROWB(h0, e0.x);
            float n0 = __int_as_float(e0.y);
            FMA4(acc, n0, h0);
        }

        // self-loop + dst scale (dn==0 for invalid nodes -> acc=0, harmless)
        float4 sv = make_float4(bf2f(svq.x), bf2f(svq.y), bf2f(svq.z), bf2f(svq.w));
        acc.x = fmaf(dn, sv.x, acc.x) * dn;
        acc.y = fmaf(dn, sv.y, acc.y) * dn;
        acc.z = fmaf(dn, sv.z, acc.z) * dn;
        acc.w = fmaf(dn, sv.w, acc.w) * dn;
        *reinterpret_cast<float4*>(&rowbuf[wv][g][l * 4]) = acc;
        __builtin_amdgcn_wave_barrier();

        // epilogue: 4 nodes sequentially; rowbuf reads broadcast, Wlds conflict-free
        #pragma unroll 1
        for (int j = 0; j < 4; j++) {
            int onode = base + j;
            if (onode >= n) break;
            float o = 0.f;
            #pragma unroll
            for (int k = 0; k < 64; k++)
                o = fmaf(rowbuf[wv][j][k], Wlds[k][lane], o);
            o += bl;
            if (RELU) {
                o = fmaxf(o, 0.f);
                OutB[(size_t)onode * DIM + lane] = f2bf(o);
            } else {
                OutF[(size_t)onode * DIM + lane] = o;
            }
        }
        __builtin_amdgcn_wave_barrier();
    }
}

extern "C" void kernel_launch(void* const* d_in, const int* in_sizes, int n_in,
                              void* d_out, int out_size, void* d_ws, size_t ws_size,
                              hipStream_t stream) {
    const float* x  = (const float*)d_in[0];
    const int* ei   = (const int*)d_in[1];   // [2][NE] int32
    const float* ew = (const float*)d_in[2];
    const float* W1 = (const float*)d_in[3];
    const float* b1 = (const float*)d_in[4];
    const float* W2 = (const float*)d_in[5];
    const float* b2 = (const float*)d_in[6];
    const float* W3 = (const float*)d_in[7];
    const float* b3 = (const float*)d_in[8];
    float* out = (float*)d_out;

    const int* src = ei;
    const int* dst = ei + NE;

    auto align = [](size_t v) { return (v + 255) / 256 * 256; };
    char* ws = (char*)d_ws;
    // persistent through layers:
    int*   row_ptr = (int*)ws;   ws += align(((size_t)NN + 1) * 4);
    float* dinv    = (float*)ws; ws += align((size_t)NN * 4);
    int2*  edata   = (int2*)ws;  ws += align((size_t)NE * 8);              // 12.8 MB
    // build temporaries, later overlaid by Hb0 (all dead after k_group):
    char* temp = ws;
    int*  gcounts = (int*)temp;                 // 4 MB
    int*  bintot  = (int*)(temp + align((size_t)NBINP * NCHUNKP * 4));
    int*  binbase = (int*)((char*)bintot + align((size_t)NBINP * 4));
    int2* binned  = (int2*)((char*)binbase + align(((size_t)NBINP + 1) * 4)); // 12.8 MB
    ws += align((size_t)NBINP * NCHUNKP * 4) + align((size_t)NBINP * 4)
        + align(((size_t)NBINP + 1) * 4) + align((size_t)NE * 8);
    ushort* Hb0 = (ushort*)temp;                // 12.8 MB, overlays dead build temps
    // bf16 activations:
    ushort* A1b = (ushort*)ws; ws += align((size_t)NN * DIM * 2);          // 12.8 MB
    ushort* A2b = (ushort*)ws;                                             // 12.8 MB

    const int gE = (NE + 255) / 256;
    const int gC = (NN * DIM / 4 + 255) / 256;
    const int gL = 2048;

    // ---- deterministic CSR build: zero global atomics ----
    k_hist<<<NCHUNKP, 256, 0, stream>>>(dst, gcounts);
    k_colscan<<<NBINP, 256, 0, stream>>>(gcounts, bintot);
    k_binscan<<<1, 256, 0, stream>>>(bintot, binbase, row_ptr);
    k_scatbin<<<NCHUNKP, 256, 0, stream>>>(src, dst, ew, gcounts, binbase, binned);
    k_group<<<NBIN, 256, 0, stream>>>(binned, binbase, edata, row_ptr, dinv);
    k_norm<<<gE, 256, 0, stream>>>(edata, dinv, NE);
    k_cvt<<<gC, 256, 0, stream>>>(x, Hb0, NN * DIM / 4);   // after k_group (overlay)

    // ---- fused layers: bf16 gather tables, fp32 math ----
    k_layer<1><<<gL, 256, 0, stream>>>(row_ptr, edata, Hb0, W1, b1, dinv, A1b, nullptr, NN);
    k_layer<1><<<gL, 256, 0, stream>>>(row_ptr, edata, A1b, W2, b2, dinv, A2b, nullptr, NN);
    k_layer<0><<<gL, 256, 0, stream>>>(row_ptr, edata, A2b, W3, b3, dinv, nullptr, out, NN);
}